// Round 12
// baseline (1418.217 us; speedup 1.0000x reference)
//
#include <hip/hip_runtime.h>
#include <math.h>

// Problem constants (match reference)
#define BATCH    8
#define NFFT     1024
#define HOPSZ    256
#define NBINS    513        // NFFT/2 + 1
#define SROW     516        // padded row stride (elements) for spec/mag rows
#define TFRAMES  1024       // frames per batch (== T)
#define NBLK     (BATCH * TFRAMES)     // 8192 rows
#define LOUT     261888     // HOP*(T-1) : audio length per batch
#define YLEN     262912     // NFFT + HOP*(TFRAMES-1) = 1027*256
#define NITER    32
#define TT       8          // t-tile in k_specinit

// LDS skew: physical = i + i/32 → breaks power-of-2 stride bank conflicts
#define LDSIDX(i) ((i) + ((i) >> 5))
#define LDSBUF    532       // LDSIDX(512)=528 + headroom

// Wave-local LDS sync: per-wave scratch only, DS ops within a wave complete
// in order; replaces __syncthreads (validated rounds 2-11).
__device__ __forceinline__ void wsync() {
    __asm__ volatile("s_waitcnt lgkmcnt(0)" ::: "memory");
}

// ---------------------------------------------------------------------------
// 8-point DFT in registers. SIGN=-1 forward, +1 inverse (unscaled).
// ---------------------------------------------------------------------------
template <int SIGN>
__device__ __forceinline__ void dft8(const float xr[8], const float xi[8],
                                     float yr[8], float yi[8])
{
    const float r2 = 0.70710678118654752f;
    float Ar = xr[0] + xr[4], Ai = xi[0] + xi[4];
    float Br = xr[0] - xr[4], Bi = xi[0] - xi[4];
    float Cr = xr[2] + xr[6], Ci = xi[2] + xi[6];
    float Dr = xr[2] - xr[6], Di = xi[2] - xi[6];
    float E0r = Ar + Cr, E0i = Ai + Ci;
    float E2r = Ar - Cr, E2i = Ai - Ci;
    float E1r, E1i, E3r, E3i;
    if (SIGN < 0) { E1r = Br + Di; E1i = Bi - Dr; E3r = Br - Di; E3i = Bi + Dr; }
    else          { E1r = Br - Di; E1i = Bi + Dr; E3r = Br + Di; E3i = Bi - Dr; }
    float ar = xr[1] + xr[5], ai = xi[1] + xi[5];
    float br = xr[1] - xr[5], bi = xi[1] - xi[5];
    float cr = xr[3] + xr[7], ci = xi[3] + xi[7];
    float dr = xr[3] - xr[7], di = xi[3] - xi[7];
    float O0r = ar + cr, O0i = ai + ci;
    float O2r = ar - cr, O2i = ai - ci;
    float O1r, O1i, O3r, O3i;
    if (SIGN < 0) { O1r = br + di; O1i = bi - dr; O3r = br - di; O3i = bi + dr; }
    else          { O1r = br - di; O1i = bi + dr; O3r = br + di; O3i = bi - dr; }
    float t1r, t1i, t2r, t2i, t3r, t3i;
    if (SIGN < 0) {
        t1r = r2 * (O1r + O1i); t1i = r2 * (O1i - O1r);
        t2r = O2i;              t2i = -O2r;
        t3r = r2 * (O3i - O3r); t3i = -r2 * (O3r + O3i);
    } else {
        t1r = r2 * (O1r - O1i); t1i = r2 * (O1i + O1r);
        t2r = -O2i;             t2i = O2r;
        t3r = -r2 * (O3r + O3i); t3i = r2 * (O3r - O3i);
    }
    yr[0] = E0r + O0r; yi[0] = E0i + O0i;  yr[4] = E0r - O0r; yi[4] = E0i - O0i;
    yr[1] = E1r + t1r; yi[1] = E1i + t1i;  yr[5] = E1r - t1r; yi[5] = E1i - t1i;
    yr[2] = E2r + t2r; yi[2] = E2i + t2i;  yr[6] = E2r - t2r; yi[6] = E2i - t2i;
    yr[3] = E3r + t3r; yi[3] = E3i + t3i;  yr[7] = E3r - t3r; yi[7] = E3i - t3i;
}

template <int SIGN, int S>
__device__ __forceinline__ void stage_write(float* lre, float* lim,
                                            const float yr[8], const float yi[8],
                                            int lane, const float2* __restrict__ tw)
{
    const int q = lane & (S - 1);
    const int p = lane / S;
    const int e = p * S;
    const int base = q + 8 * S * p;
#pragma unroll
    for (int j = 0; j < 8; ++j) {
        float vr = yr[j], vi = yi[j];
        if (j > 0) {
            float2 w = tw[j * e];
            float wr = w.x, wi = (SIGN < 0) ? w.y : -w.y;
            float tr = vr * wr - vi * wi;
            vi = vr * wi + vi * wr;
            vr = tr;
        }
        int o = LDSIDX(base + S * j);
        lre[o] = vr; lim[o] = vi;
    }
}

__device__ __forceinline__ void stage_read(const float* lre, const float* lim,
                                           float xr[8], float xi[8], int lane)
{
#pragma unroll
    for (int j = 0; j < 8; ++j) {
        int o = LDSIDX(lane + 64 * j);
        xr[j] = lre[o]; xi[j] = lim[o];
    }
}

// 512-pt FFT, 3 radix-8 stages, in-place per-wave LDS scratch, wave-local sync.
template <int SIGN>
__device__ __forceinline__ void fft512(float* lre, float* lim,
                                       float xr[8], float xi[8],
                                       float yr[8], float yi[8],
                                       int lane, const float2* __restrict__ tw)
{
    dft8<SIGN>(xr, xi, yr, yi);
    stage_write<SIGN, 1>(lre, lim, yr, yi, lane, tw);
    wsync();
    stage_read(lre, lim, xr, xi, lane);
    wsync();
    dft8<SIGN>(xr, xi, yr, yi);
    stage_write<SIGN, 8>(lre, lim, yr, yi, lane, tw);
    wsync();
    stage_read(lre, lim, xr, xi, lane);
    dft8<SIGN>(xr, xi, yr, yi);           // stage2: p=0 → no twiddles, stays in regs
}

// Variant with stage-0 input already in LDS (positions lane+64j).
template <int SIGN>
__device__ __forceinline__ void fft512_lds(float* lre, float* lim,
                                           float xr[8], float xi[8],
                                           float yr[8], float yi[8],
                                           int lane, const float2* __restrict__ tw)
{
    stage_read(lre, lim, xr, xi, lane);
    wsync();
    fft512<SIGN>(lre, lim, xr, xi, yr, yi, lane, tw);
}

// Load windowed 1024-sample frame f from audioR (already /wsq) → packed regs.
__device__ __forceinline__ void load_window(const float* __restrict__ ab, int f,
                                            const float* __restrict__ win,
                                            float xr[8], float xi[8], int lane)
{
    if (f >= 2 && f <= 1021) {
        const float* src = ab + f * HOPSZ;
#pragma unroll
        for (int j = 0; j < 8; ++j) {
            int n0 = 2 * (lane + 64 * j);
            float2 s = *(const float2*)&src[n0];
            float2 w2 = *(const float2*)&win[n0];
            xr[j] = s.x * w2.x;
            xi[j] = s.y * w2.y;
        }
    } else {
#pragma unroll
        for (int j = 0; j < 8; ++j) {
            int n0 = 2 * (lane + 64 * j);
            int j0 = f * HOPSZ + n0 - 512;
            int ja = (j0 < 0) ? -j0 : ((j0 >= LOUT) ? 2 * LOUT - 2 - j0 : j0);
            int j1 = j0 + 1;
            int jb = (j1 < 0) ? -j1 : ((j1 >= LOUT) ? 2 * LOUT - 2 - j1 : j1);
            float s0 = ab[ja + 512];
            float s1 = ab[jb + 512];
            float2 w2 = *(const float2*)&win[n0];
            xr[j] = s0 * w2.x;
            xi[j] = s1 * w2.y;
        }
    }
}

// Hermitian post-twist for pair r (p=lane+64r, q=512-p): Z (in LDS) → X[p],X[q].
__device__ __forceinline__ void posttwist_pair(const float* lre, const float* lim,
                                               const float2* __restrict__ twh,
                                               int p,
                                               float& Xpr, float& Xpi,
                                               float& Xqr, float& Xqi)
{
    int pm = (512 - p) & 511;
    float Zkr = lre[LDSIDX(p)],  Zki = lim[LDSIDX(p)];
    float Zmr = lre[LDSIDX(pm)], Zmi = lim[LDSIDX(pm)];
    float Ar = 0.5f * (Zkr + Zmr), Ai = 0.5f * (Zki - Zmi);
    float Sr = 0.5f * (Zkr - Zmr), Si = 0.5f * (Zki + Zmi);
    float2 W1 = twh[p];
    float U1r = W1.x * Sr - W1.y * Si, U1i = W1.x * Si + W1.y * Sr;
    Xpr = Ar + U1i; Xpi = Ai - U1r;
    float w2r, w2i;
    if (p == 0) { w2r = -1.f; w2i = 0.f; }
    else { float2 W2 = twh[512 - p]; w2r = W2.x; w2i = W2.y; }
    float U2r = -w2r * Sr - w2i * Si, U2i = w2r * Si - w2i * Sr;
    Xqr = Ar + U2i; Xqi = -Ai - U2r;
}

// ---------------------------------------------------------------------------
// Setup: twiddles, window tables, melinv transpose, wsq_inv — one kernel.
// ---------------------------------------------------------------------------
__global__ void k_setup(float2* tw512, float2* twh, float* win, float* wscl,
                        const float* __restrict__ melinv, float* __restrict__ melinvT,
                        float* __restrict__ wsqinv)
{
    int idx = blockIdx.x * blockDim.x + threadIdx.x;
    if (idx < 512) {
        double t1 = -2.0 * M_PI * (double)idx / 512.0;
        tw512[idx] = make_float2((float)cos(t1), (float)sin(t1));
        double t2 = -2.0 * M_PI * (double)idx / 1024.0;
        twh[idx] = make_float2((float)cos(t2), (float)sin(t2));
    }
    if (idx < 1024) {
        double w = 0.5 - 0.5 * cos(2.0 * M_PI * (double)idx / 1024.0);
        win[idx]  = (float)w;
        wscl[idx] = (float)(w / 512.0);
    }
    if (idx < 80 * NBINS) {
        int m = idx / NBINS, k = idx - m * NBINS;
        melinvT[idx] = melinv[k * 80 + m];
    }
    if (idx < YLEN) {
        int t = idx;
        int fhi = t >> 8;
        int flo = fhi - 3; if (flo < 0) flo = 0;
        if (fhi > TFRAMES - 1) fhi = TFRAMES - 1;
        float acc = 0.f;
        for (int f = flo; f <= fhi; ++f) {
            int n = t - (f << 8);
            float w = (float)(0.5 - 0.5 * cos(2.0 * M_PI * (double)n / 1024.0));
            acc += w * w;
        }
        float m = acc > 1e-8f ? acc : 1e-8f;
        wsqinv[t] = 1.0f / m;
    }
}

// ---------------------------------------------------------------------------
// specinit, t-tiled (TT=8, 1024 blocks): em[80][8] in LDS; thread owns bin k
// (2 passes + k=512 on tid 0). ang0 read as 32B chunks. mag fp32 (MUST be —
// fp16 state in the GL loop fails, rounds 6/9).
// ---------------------------------------------------------------------------
__global__ __launch_bounds__(256) void k_specinit(const float* __restrict__ mel,
                                                  const float* __restrict__ melinvT,
                                                  const float* __restrict__ ang0,
                                                  float* __restrict__ mag,
                                                  float2* __restrict__ spec)
{
    int b = blockIdx.y;
    int t0 = blockIdx.x * TT;
    int tid = threadIdx.x;
    __shared__ float em[80 * TT];
    for (int i = tid; i < 80 * TT; i += 256) {
        int m = i >> 3, tt = i & (TT - 1);
        em[i] = expf(mel[((size_t)b * 80 + m) * 1024 + t0 + tt]);
    }
    __syncthreads();

#pragma unroll
    for (int pass = 0; pass < 3; ++pass) {
        int k;
        if (pass < 2) k = tid + 256 * pass;
        else { if (tid != 0) break; k = 512; }

        float acc[TT];
#pragma unroll
        for (int tt = 0; tt < TT; ++tt) acc[tt] = 0.f;
        for (int m = 0; m < 80; ++m) {
            float wv = melinvT[m * NBINS + k];
            const float4 e0 = *(const float4*)&em[m * TT + 0];
            const float4 e1 = *(const float4*)&em[m * TT + 4];
            acc[0] = fmaf(wv, e0.x, acc[0]);  acc[1] = fmaf(wv, e0.y, acc[1]);
            acc[2] = fmaf(wv, e0.z, acc[2]);  acc[3] = fmaf(wv, e0.w, acc[3]);
            acc[4] = fmaf(wv, e1.x, acc[4]);  acc[5] = fmaf(wv, e1.y, acc[5]);
            acc[6] = fmaf(wv, e1.z, acc[6]);  acc[7] = fmaf(wv, e1.w, acc[7]);
        }
        const float* ap = ang0 + ((size_t)b * NBINS + k) * 1024 + t0;
        float av[TT];
        *(float4*)&av[0] = *(const float4*)(ap);
        *(float4*)&av[4] = *(const float4*)(ap + 4);
#pragma unroll
        for (int tt = 0; tt < TT; ++tt) {
            float mg = fabsf(acc[tt]);
            float sn, cn;
            sincospif(2.0f * av[tt], &sn, &cn);
            size_t row = ((size_t)b * 1024 + (t0 + tt)) * SROW;
            mag[row + k] = mg;
            spec[row + k] = make_float2(mg * cn, mg * sn);
        }
    }
}

// ---------------------------------------------------------------------------
// Initial ISTFT half (reads fp32 spec = Sc*angles0), frames out windowed.
// ---------------------------------------------------------------------------
__global__ __launch_bounds__(256) void k_ifft(const float2* __restrict__ spec,
                                              const float2* __restrict__ tw512,
                                              const float2* __restrict__ twh,
                                              const float* __restrict__ wscl,
                                              float* __restrict__ frames)
{
    __shared__ float scr[4][2][LDSBUF];
    int tid = threadIdx.x;
    int w = tid >> 6, lane = tid & 63;
    int blk = blockIdx.x * 4 + w;
    size_t row = (size_t)blk * SROW;
    float* lre = scr[w][0];
    float* lim = scr[w][1];
    float xr[8], xi[8], yr[8], yi[8];
#pragma unroll
    for (int r = 0; r < 8; ++r) {
        int k = lane + 64 * r;
        float2 v1 = spec[row + k];
        float2 v2 = spec[row + 512 - k];
        if (k == 0) { v1.y = 0.f; v2.y = 0.f; }
        float Ar = 0.5f * (v1.x + v2.x), Ai = 0.5f * (v1.y - v2.y);
        float Sr = 0.5f * (v1.x - v2.x), Si = 0.5f * (v1.y + v2.y);
        float2 W = twh[k];
        float Xor = W.x * Sr + W.y * Si;
        float Xoi = W.x * Si - W.y * Sr;
        xr[r] = Ar - Xoi;
        xi[r] = Ai + Xor;
    }
    fft512<1>(lre, lim, xr, xi, yr, yi, lane, tw512);
    size_t frow = (size_t)blk * 1024;
#pragma unroll
    for (int j = 0; j < 8; ++j) {
        int m = lane + 64 * j;
        float2 ws = *(const float2*)&wscl[2 * m];
        float2 o;
        o.x = yr[j] * ws.x;
        o.y = yi[j] * ws.y;
        *(float2*)&frames[frow + 2 * m] = o;
    }
}

// ---------------------------------------------------------------------------
// Overlap-add: audioR[b][t] = (sum of <=4 frames at t) * wsqinv[t], float4.
// ---------------------------------------------------------------------------
__global__ __launch_bounds__(256) void k_oa(const float* __restrict__ frames,
                                            const float* __restrict__ wsqinv,
                                            float* __restrict__ audioR)
{
    int t4 = (blockIdx.x * 256 + threadIdx.x) * 4;
    if (t4 >= YLEN) return;
    int b = blockIdx.y;
    const float* fb = frames + (size_t)b * (TFRAMES * 1024);
    int fhi = t4 >> 8;
    int flo = fhi - 3; if (flo < 0) flo = 0;
    if (fhi > TFRAMES - 1) fhi = TFRAMES - 1;
    float4 acc = make_float4(0.f, 0.f, 0.f, 0.f);
    for (int ff = flo; ff <= fhi; ++ff) {
        float4 v = *(const float4*)&fb[(size_t)ff * 1024 + (t4 - (ff << 8))];
        acc.x += v.x; acc.y += v.y; acc.z += v.z; acc.w += v.w;
    }
    float4 wq = *(const float4*)&wsqinv[t4];
    acc.x *= wq.x; acc.y *= wq.y; acc.z *= wq.z; acc.w *= wq.w;
    *(float4*)&audioR[(size_t)b * YLEN + t4] = acc;
}

// ---------------------------------------------------------------------------
// FUSED, rebp-free: X_prev is RECOMPUTED from the previous audio buffer with
// a second forward FFT (bit-identical to the value round-10 stored in rebp),
// so the 67 MB/iter rebp stream disappears. 3 FFTs per wave. All fp32.
// ---------------------------------------------------------------------------
__global__ __launch_bounds__(256) void k_fused(const float* __restrict__ audioCur,
                                               const float* __restrict__ audioPrev,
                                               const float* __restrict__ mag,
                                               const float2* __restrict__ tw512,
                                               const float2* __restrict__ twh,
                                               const float* __restrict__ win,
                                               const float* __restrict__ wscl,
                                               float* __restrict__ frames,
                                               float beta)
{
    __shared__ float scr[4][2][LDSBUF];
    int tid = threadIdx.x;
    int w = tid >> 6, lane = tid & 63;
    int blk = blockIdx.x * 4 + w;
    int b = blk >> 10;
    int f = blk & 1023;
    float* lre = scr[w][0];
    float* lim = scr[w][1];
    float xr[8], xi[8], yr[8], yi[8];

    // ---- X_prev: forward FFT of previous audio (skipped when beta==0) ----
    float xpPr[4], xpPi[4], xqPr[4], xqPi[4];
    float xcPr = 0.f, xcPi = 0.f;
    if (beta != 0.f) {
        const float* abp = audioPrev + (size_t)b * YLEN;
        load_window(abp, f, win, xr, xi, lane);
        fft512<-1>(lre, lim, xr, xi, yr, yi, lane, tw512);
#pragma unroll
        for (int j = 0; j < 8; ++j) {
            int o = LDSIDX(lane + 64 * j);
            lre[o] = yr[j]; lim[o] = yi[j];
        }
        wsync();
#pragma unroll
        for (int r = 0; r < 4; ++r)
            posttwist_pair(lre, lim, twh, lane + 64 * r,
                           xpPr[r], xpPi[r], xqPr[r], xqPi[r]);
        if (lane == 0) {   // center bin 256: X = conj(Z)
            xcPr = lre[LDSIDX(256)];
            xcPi = -lim[LDSIDX(256)];
        }
        wsync();   // pair reads complete before next FFT's stage writes
    } else {
#pragma unroll
        for (int r = 0; r < 4; ++r) {
            xpPr[r] = 0.f; xpPi[r] = 0.f; xqPr[r] = 0.f; xqPi[r] = 0.f;
        }
    }

    // ---- X: forward FFT of current audio ----
    const float* ab = audioCur + (size_t)b * YLEN;
    load_window(ab, f, win, xr, xi, lane);
    fft512<-1>(lre, lim, xr, xi, yr, yi, lane, tw512);
#pragma unroll
    for (int j = 0; j < 8; ++j) {
        int o = LDSIDX(lane + 64 * j);
        lre[o] = yr[j]; lim[o] = yi[j];
    }
    wsync();

    // ---- in-place pair pass: post-twist → GL update → pre-twist ----
    size_t row = (size_t)blk * SROW;
#pragma unroll
    for (int r = 0; r < 4; ++r) {
        int p = lane + 64 * r;
        int q = 512 - p;
        float Xpr, Xpi, Xqr, Xqi;
        posttwist_pair(lre, lim, twh, p, Xpr, Xpi, Xqr, Xqi);
        float2 W1 = twh[p];
        float w2r, w2i;
        if (p == 0) { w2r = -1.f; w2i = 0.f; }
        else { float2 W2 = twh[512 - p]; w2r = W2.x; w2i = W2.y; }
        float v1x = Xpr - beta * xpPr[r], v1y = Xpi - beta * xpPi[r];
        float v2x = Xqr - beta * xqPr[r], v2y = Xqi - beta * xqPi[r];
        float a1 = sqrtf(v1x * v1x + v1y * v1y) + 1e-16f;
        float a2 = sqrtf(v2x * v2x + v2y * v2y) + 1e-16f;
        float sc1 = mag[row + p] / a1;
        float sc2 = mag[row + q] / a2;
        float s1x = v1x * sc1, s1y = v1y * sc1;
        float s2x = v2x * sc2, s2y = v2y * sc2;
        float Apr = 0.5f * (s1x + s2x), Api = 0.5f * (s1y - s2y);
        float Spr = 0.5f * (s1x - s2x), Spi = 0.5f * (s1y + s2y);
        float Xor = W1.x * Spr + W1.y * Spi;
        float Xoi = W1.x * Spi - W1.y * Spr;
        lre[LDSIDX(p)] = Apr - Xoi;
        lim[LDSIDX(p)] = Api + Xor;
        if (p > 0) {
            float Yor = -w2r * Spr + w2i * Spi;
            float Yoi =  w2r * Spi + w2i * Spr;
            lre[LDSIDX(512 - p)] = Apr - Yoi;
            lim[LDSIDX(512 - p)] = -Api + Yor;
        }
    }
    if (lane == 0) {   // center bin 256: X = conj(Z), Z' = conj(s)
        float Zr = lre[LDSIDX(256)], Zi = lim[LDSIDX(256)];
        float Xr = Zr, Xi = -Zi;
        float vx = Xr - beta * xcPr, vy = Xi - beta * xcPi;
        float a = sqrtf(vx * vx + vy * vy) + 1e-16f;
        float sc = mag[row + 256] / a;
        lre[LDSIDX(256)] = vx * sc;
        lim[LDSIDX(256)] = -(vy * sc);
    }
    wsync();

    // ---- inverse FFT from LDS, write windowed frames ----
    fft512_lds<1>(lre, lim, xr, xi, yr, yi, lane, tw512);
    size_t frow = (size_t)blk * 1024;
#pragma unroll
    for (int j = 0; j < 8; ++j) {
        int m = lane + 64 * j;
        float2 ws = *(const float2*)&wscl[2 * m];
        float2 o;
        o.x = yr[j] * ws.x;
        o.y = yi[j] * ws.y;
        *(float2*)&frames[frow + 2 * m] = o;
    }
}

// Final overlap-add -> audio out (crop 512 each side), float4.
__global__ __launch_bounds__(256) void k_gather(const float* __restrict__ frames,
                                                const float* __restrict__ wsqinv,
                                                float* __restrict__ out)
{
    int idx = (blockIdx.x * 256 + threadIdx.x) * 4;
    if (idx >= BATCH * LOUT) return;
    int b = idx / LOUT;
    int j = idx - b * LOUT;
    int t4 = j + 512;
    const float* fb = frames + (size_t)b * (TFRAMES * 1024);
    int fhi = t4 >> 8;
    int flo = fhi - 3; if (flo < 0) flo = 0;
    if (fhi > TFRAMES - 1) fhi = TFRAMES - 1;
    float4 acc = make_float4(0.f, 0.f, 0.f, 0.f);
    for (int ff = flo; ff <= fhi; ++ff) {
        float4 v = *(const float4*)&fb[(size_t)ff * 1024 + (t4 - (ff << 8))];
        acc.x += v.x; acc.y += v.y; acc.z += v.z; acc.w += v.w;
    }
    float4 wq = *(const float4*)&wsqinv[t4];
    acc.x *= wq.x; acc.y *= wq.y; acc.z *= wq.z; acc.w *= wq.w;
    *(float4*)&out[idx] = acc;
}

// ---------------------------------------------------------------------------
extern "C" void kernel_launch(void* const* d_in, const int* in_sizes, int n_in,
                              void* d_out, int out_size, void* d_ws, size_t ws_size,
                              hipStream_t stream)
{
    const float* mel    = (const float*)d_in[0];   // [8, 80, 1024]
    const float* melinv = (const float*)d_in[1];   // [513, 80]
    const float* ang0   = (const float*)d_in[2];   // [8, 513, 1024]
    float* out = (float*)d_out;                    // [8, 261888]

    char* ws = (char*)d_ws;
    size_t off = 0;
    auto carve = [&](size_t bytes) -> void* {
        void* p = ws + off;
        off += (bytes + 255) & ~(size_t)255;
        return p;
    };
    float2* tw512   = (float2*)carve(512 * sizeof(float2));
    float2* twh     = (float2*)carve(512 * sizeof(float2));
    float*  win     = (float*) carve(1024 * sizeof(float));
    float*  wscl    = (float*) carve(1024 * sizeof(float));
    float*  wsqinv  = (float*) carve((size_t)YLEN * sizeof(float));
    float*  melinvT = (float*) carve((size_t)80 * NBINS * sizeof(float));
    float*  mag     = (float*) carve((size_t)NBLK * SROW * sizeof(float));
    float2* spec    = (float2*)carve((size_t)NBLK * SROW * sizeof(float2));
    float*  frames  = (float*) carve((size_t)NBLK * 1024 * sizeof(float));
    float*  audioU  = (float*) carve((size_t)BATCH * YLEN * sizeof(float));
    float*  audioV  = (float*) carve((size_t)BATCH * YLEN * sizeof(float));
    (void)ws_size; (void)in_sizes; (void)n_in; (void)out_size;

    const float beta = (float)(0.99 / 1.99);

    hipLaunchKernelGGL(k_setup, dim3((YLEN + 255) / 256), dim3(256), 0, stream,
                       tw512, twh, win, wscl, melinv, melinvT, wsqinv);
    hipLaunchKernelGGL(k_specinit, dim3(TFRAMES / TT, BATCH), dim3(256), 0, stream,
                       mel, melinvT, ang0, mag, spec);

    // Initial ISTFT of Sc*angles0 → frames
    hipLaunchKernelGGL(k_ifft, dim3(NBLK / 4), dim3(256), 0, stream,
                       spec, tw512, twh, wscl, frames);
    // 32 fused GL iterations. audio ping-pong: k_oa(i) writes cur=U/V by parity;
    // k_fused(i) reads cur + prev (prev unread when beta==0 at i=0).
    for (int it = 0; it < NITER; ++it) {
        float* cur  = (it & 1) ? audioV : audioU;
        float* prev = (it & 1) ? audioU : audioV;
        float b_it = (it == 0) ? 0.f : beta;
        hipLaunchKernelGGL(k_oa, dim3((YLEN / 4 + 255) / 256, BATCH), dim3(256), 0,
                           stream, frames, wsqinv, cur);
        hipLaunchKernelGGL(k_fused, dim3(NBLK / 4), dim3(256), 0, stream,
                           cur, prev, mag, tw512, twh, win, wscl, frames, b_it);
    }
    hipLaunchKernelGGL(k_gather, dim3(BATCH * LOUT / 4 / 256), dim3(256), 0, stream,
                       frames, wsqinv, out);
}

// Round 13
// 1232.518 us; speedup vs baseline: 1.1507x; 1.1507x over previous
//
#include <hip/hip_runtime.h>
#include <math.h>

// Problem constants (match reference)
#define BATCH    8
#define NFFT     1024
#define HOPSZ    256
#define NBINS    513        // NFFT/2 + 1
#define SROW     516        // padded row stride (elements) for spec/mag/rebprev rows
#define TFRAMES  1024       // frames per batch (== T)
#define NBLK     (BATCH * TFRAMES)     // 8192 rows
#define LOUT     261888     // HOP*(T-1) : audio length per batch
#define YLEN     262912     // NFFT + HOP*(TFRAMES-1) = 1027*256
#define NITER    32
#define TT       8          // t-tile in k_specinit (bit-exact vs TT=16, round 11)

// LDS skew: physical = i + i/32 → breaks power-of-2 stride bank conflicts
#define LDSIDX(i) ((i) + ((i) >> 5))
#define LDSBUF    532       // LDSIDX(512)=528 + headroom

// Wave-local LDS sync: per-wave scratch only, DS ops within a wave complete
// in order; replaces __syncthreads (validated rounds 2-12).
__device__ __forceinline__ void wsync() {
    __asm__ volatile("s_waitcnt lgkmcnt(0)" ::: "memory");
}

// ---------------------------------------------------------------------------
// 8-point DFT in registers. SIGN=-1 forward, +1 inverse (unscaled).
// ---------------------------------------------------------------------------
template <int SIGN>
__device__ __forceinline__ void dft8(const float xr[8], const float xi[8],
                                     float yr[8], float yi[8])
{
    const float r2 = 0.70710678118654752f;
    float Ar = xr[0] + xr[4], Ai = xi[0] + xi[4];
    float Br = xr[0] - xr[4], Bi = xi[0] - xi[4];
    float Cr = xr[2] + xr[6], Ci = xi[2] + xi[6];
    float Dr = xr[2] - xr[6], Di = xi[2] - xi[6];
    float E0r = Ar + Cr, E0i = Ai + Ci;
    float E2r = Ar - Cr, E2i = Ai - Ci;
    float E1r, E1i, E3r, E3i;
    if (SIGN < 0) { E1r = Br + Di; E1i = Bi - Dr; E3r = Br - Di; E3i = Bi + Dr; }
    else          { E1r = Br - Di; E1i = Bi + Dr; E3r = Br + Di; E3i = Bi - Dr; }
    float ar = xr[1] + xr[5], ai = xi[1] + xi[5];
    float br = xr[1] - xr[5], bi = xi[1] - xi[5];
    float cr = xr[3] + xr[7], ci = xi[3] + xi[7];
    float dr = xr[3] - xr[7], di = xi[3] - xi[7];
    float O0r = ar + cr, O0i = ai + ci;
    float O2r = ar - cr, O2i = ai - ci;
    float O1r, O1i, O3r, O3i;
    if (SIGN < 0) { O1r = br + di; O1i = bi - dr; O3r = br - di; O3i = bi + dr; }
    else          { O1r = br - di; O1i = bi + dr; O3r = br + di; O3i = bi - dr; }
    float t1r, t1i, t2r, t2i, t3r, t3i;
    if (SIGN < 0) {
        t1r = r2 * (O1r + O1i); t1i = r2 * (O1i - O1r);
        t2r = O2i;              t2i = -O2r;
        t3r = r2 * (O3i - O3r); t3i = -r2 * (O3r + O3i);
    } else {
        t1r = r2 * (O1r - O1i); t1i = r2 * (O1i + O1r);
        t2r = -O2i;             t2i = O2r;
        t3r = -r2 * (O3r + O3i); t3i = r2 * (O3r - O3i);
    }
    yr[0] = E0r + O0r; yi[0] = E0i + O0i;  yr[4] = E0r - O0r; yi[4] = E0i - O0i;
    yr[1] = E1r + t1r; yi[1] = E1i + t1i;  yr[5] = E1r - t1r; yi[5] = E1i - t1i;
    yr[2] = E2r + t2r; yi[2] = E2i + t2i;  yr[6] = E2r - t2r; yi[6] = E2i - t2i;
    yr[3] = E3r + t3r; yi[3] = E3i + t3i;  yr[7] = E3r - t3r; yi[7] = E3i - t3i;
}

template <int SIGN, int S>
__device__ __forceinline__ void stage_write(float* lre, float* lim,
                                            const float yr[8], const float yi[8],
                                            int lane, const float2* __restrict__ tw)
{
    const int q = lane & (S - 1);
    const int p = lane / S;
    const int e = p * S;
    const int base = q + 8 * S * p;
#pragma unroll
    for (int j = 0; j < 8; ++j) {
        float vr = yr[j], vi = yi[j];
        if (j > 0) {
            float2 w = tw[j * e];
            float wr = w.x, wi = (SIGN < 0) ? w.y : -w.y;
            float tr = vr * wr - vi * wi;
            vi = vr * wi + vi * wr;
            vr = tr;
        }
        int o = LDSIDX(base + S * j);
        lre[o] = vr; lim[o] = vi;
    }
}

__device__ __forceinline__ void stage_read(const float* lre, const float* lim,
                                           float xr[8], float xi[8], int lane)
{
#pragma unroll
    for (int j = 0; j < 8; ++j) {
        int o = LDSIDX(lane + 64 * j);
        xr[j] = lre[o]; xi[j] = lim[o];
    }
}

// 512-pt FFT, 3 radix-8 stages, in-place per-wave LDS scratch, wave-local sync.
template <int SIGN>
__device__ __forceinline__ void fft512(float* lre, float* lim,
                                       float xr[8], float xi[8],
                                       float yr[8], float yi[8],
                                       int lane, const float2* __restrict__ tw)
{
    dft8<SIGN>(xr, xi, yr, yi);
    stage_write<SIGN, 1>(lre, lim, yr, yi, lane, tw);
    wsync();
    stage_read(lre, lim, xr, xi, lane);
    wsync();
    dft8<SIGN>(xr, xi, yr, yi);
    stage_write<SIGN, 8>(lre, lim, yr, yi, lane, tw);
    wsync();
    stage_read(lre, lim, xr, xi, lane);
    dft8<SIGN>(xr, xi, yr, yi);           // stage2: p=0 → no twiddles, stays in regs
}

// Variant with stage-0 input already in LDS (positions lane+64j).
template <int SIGN>
__device__ __forceinline__ void fft512_lds(float* lre, float* lim,
                                           float xr[8], float xi[8],
                                           float yr[8], float yi[8],
                                           int lane, const float2* __restrict__ tw)
{
    stage_read(lre, lim, xr, xi, lane);
    wsync();
    fft512<SIGN>(lre, lim, xr, xi, yr, yi, lane, tw);
}

// ---------------------------------------------------------------------------
// Setup: twiddles, window tables, melinv transpose, wsq_inv — one kernel.
// ---------------------------------------------------------------------------
__global__ void k_setup(float2* tw512, float2* twh, float* win, float* wscl,
                        const float* __restrict__ melinv, float* __restrict__ melinvT,
                        float* __restrict__ wsqinv)
{
    int idx = blockIdx.x * blockDim.x + threadIdx.x;
    if (idx < 512) {
        double t1 = -2.0 * M_PI * (double)idx / 512.0;
        tw512[idx] = make_float2((float)cos(t1), (float)sin(t1));
        double t2 = -2.0 * M_PI * (double)idx / 1024.0;
        twh[idx] = make_float2((float)cos(t2), (float)sin(t2));
    }
    if (idx < 1024) {
        double w = 0.5 - 0.5 * cos(2.0 * M_PI * (double)idx / 1024.0);
        win[idx]  = (float)w;
        wscl[idx] = (float)(w / 512.0);
    }
    if (idx < 80 * NBINS) {
        int m = idx / NBINS, k = idx - m * NBINS;
        melinvT[idx] = melinv[k * 80 + m];
    }
    if (idx < YLEN) {
        int t = idx;
        int fhi = t >> 8;
        int flo = fhi - 3; if (flo < 0) flo = 0;
        if (fhi > TFRAMES - 1) fhi = TFRAMES - 1;
        float acc = 0.f;
        for (int f = flo; f <= fhi; ++f) {
            int n = t - (f << 8);
            float w = (float)(0.5 - 0.5 * cos(2.0 * M_PI * (double)n / 1024.0));
            acc += w * w;
        }
        float m = acc > 1e-8f ? acc : 1e-8f;
        wsqinv[t] = 1.0f / m;
    }
}

// ---------------------------------------------------------------------------
// specinit, t-tiled (TT=8, 2048 blocks): em[80][8] in LDS; thread owns bin k
// (2 passes + k=512 on tid 0). ang0 read as 32B chunks. mag fp32 (MUST be —
// fp16 state anywhere in the GL loop fails: rounds 6/9).
// ---------------------------------------------------------------------------
__global__ __launch_bounds__(256) void k_specinit(const float* __restrict__ mel,
                                                  const float* __restrict__ melinvT,
                                                  const float* __restrict__ ang0,
                                                  float* __restrict__ mag,
                                                  float2* __restrict__ spec)
{
    int b = blockIdx.y;
    int t0 = blockIdx.x * TT;
    int tid = threadIdx.x;
    __shared__ float em[80 * TT];
    for (int i = tid; i < 80 * TT; i += 256) {
        int m = i >> 3, tt = i & (TT - 1);
        em[i] = expf(mel[((size_t)b * 80 + m) * 1024 + t0 + tt]);
    }
    __syncthreads();

#pragma unroll
    for (int pass = 0; pass < 3; ++pass) {
        int k;
        if (pass < 2) k = tid + 256 * pass;
        else { if (tid != 0) break; k = 512; }

        float acc[TT];
#pragma unroll
        for (int tt = 0; tt < TT; ++tt) acc[tt] = 0.f;
        for (int m = 0; m < 80; ++m) {
            float wv = melinvT[m * NBINS + k];
            const float4 e0 = *(const float4*)&em[m * TT + 0];
            const float4 e1 = *(const float4*)&em[m * TT + 4];
            acc[0] = fmaf(wv, e0.x, acc[0]);  acc[1] = fmaf(wv, e0.y, acc[1]);
            acc[2] = fmaf(wv, e0.z, acc[2]);  acc[3] = fmaf(wv, e0.w, acc[3]);
            acc[4] = fmaf(wv, e1.x, acc[4]);  acc[5] = fmaf(wv, e1.y, acc[5]);
            acc[6] = fmaf(wv, e1.z, acc[6]);  acc[7] = fmaf(wv, e1.w, acc[7]);
        }
        const float* ap = ang0 + ((size_t)b * NBINS + k) * 1024 + t0;
        float av[TT];
        *(float4*)&av[0] = *(const float4*)(ap);
        *(float4*)&av[4] = *(const float4*)(ap + 4);
#pragma unroll
        for (int tt = 0; tt < TT; ++tt) {
            float mg = fabsf(acc[tt]);
            float sn, cn;
            sincospif(2.0f * av[tt], &sn, &cn);
            size_t row = ((size_t)b * 1024 + (t0 + tt)) * SROW;
            mag[row + k] = mg;
            spec[row + k] = make_float2(mg * cn, mg * sn);
        }
    }
}

// ---------------------------------------------------------------------------
// Initial ISTFT half (reads fp32 spec = Sc*angles0), frames out windowed.
// ---------------------------------------------------------------------------
__global__ __launch_bounds__(256) void k_ifft(const float2* __restrict__ spec,
                                              const float2* __restrict__ tw512,
                                              const float2* __restrict__ twh,
                                              const float* __restrict__ wscl,
                                              float* __restrict__ frames)
{
    __shared__ float scr[4][2][LDSBUF];
    int tid = threadIdx.x;
    int w = tid >> 6, lane = tid & 63;
    int blk = blockIdx.x * 4 + w;
    size_t row = (size_t)blk * SROW;
    float* lre = scr[w][0];
    float* lim = scr[w][1];
    float xr[8], xi[8], yr[8], yi[8];
#pragma unroll
    for (int r = 0; r < 8; ++r) {
        int k = lane + 64 * r;
        float2 v1 = spec[row + k];
        float2 v2 = spec[row + 512 - k];
        if (k == 0) { v1.y = 0.f; v2.y = 0.f; }
        float Ar = 0.5f * (v1.x + v2.x), Ai = 0.5f * (v1.y - v2.y);
        float Sr = 0.5f * (v1.x - v2.x), Si = 0.5f * (v1.y + v2.y);
        float2 W = twh[k];
        float Xor = W.x * Sr + W.y * Si;
        float Xoi = W.x * Si - W.y * Sr;
        xr[r] = Ar - Xoi;
        xi[r] = Ai + Xor;
    }
    fft512<1>(lre, lim, xr, xi, yr, yi, lane, tw512);
    size_t frow = (size_t)blk * 1024;
#pragma unroll
    for (int j = 0; j < 8; ++j) {
        int m = lane + 64 * j;
        float2 ws = *(const float2*)&wscl[2 * m];
        float2 o;
        o.x = yr[j] * ws.x;
        o.y = yi[j] * ws.y;
        *(float2*)&frames[frow + 2 * m] = o;
    }
}

// ---------------------------------------------------------------------------
// Overlap-add: audioR[b][t] = (sum of <=4 frames at t) * wsqinv[t], float4.
// 4-chunks never cross a 256 boundary, so flo/fhi are uniform per chunk.
// ---------------------------------------------------------------------------
__global__ __launch_bounds__(256) void k_oa(const float* __restrict__ frames,
                                            const float* __restrict__ wsqinv,
                                            float* __restrict__ audioR)
{
    int t4 = (blockIdx.x * 256 + threadIdx.x) * 4;
    if (t4 >= YLEN) return;
    int b = blockIdx.y;
    const float* fb = frames + (size_t)b * (TFRAMES * 1024);
    int fhi = t4 >> 8;
    int flo = fhi - 3; if (flo < 0) flo = 0;
    if (fhi > TFRAMES - 1) fhi = TFRAMES - 1;
    float4 acc = make_float4(0.f, 0.f, 0.f, 0.f);
    for (int ff = flo; ff <= fhi; ++ff) {
        float4 v = *(const float4*)&fb[(size_t)ff * 1024 + (t4 - (ff << 8))];
        acc.x += v.x; acc.y += v.y; acc.z += v.z; acc.w += v.w;
    }
    float4 wq = *(const float4*)&wsqinv[t4];
    acc.x *= wq.x; acc.y *= wq.y; acc.z *= wq.z; acc.w *= wq.w;
    *(float4*)&audioR[(size_t)b * YLEN + t4] = acc;
}

// ---------------------------------------------------------------------------
// FUSED: STFT + Griffin-Lim phase update + ISTFT, one frame row per wave.
// In-place LDS pair pass (slot-disjoint, validated round 5). All fp32.
// beta=0 on iteration 0 makes the 0xAA-poisoned rebp harmless (validated
// bit-exact, round 11) — no memset needed.
// ---------------------------------------------------------------------------
__global__ __launch_bounds__(256) void k_fused(const float* __restrict__ audioR,
                                               const float* __restrict__ mag,
                                               const float2* __restrict__ tw512,
                                               const float2* __restrict__ twh,
                                               const float* __restrict__ win,
                                               const float* __restrict__ wscl,
                                               float2* __restrict__ rebprev,
                                               float* __restrict__ frames,
                                               float beta)
{
    __shared__ float scr[4][2][LDSBUF];
    int tid = threadIdx.x;
    int w = tid >> 6, lane = tid & 63;
    int blk = blockIdx.x * 4 + w;
    int b = blk >> 10;
    int f = blk & 1023;
    const float* ab = audioR + (size_t)b * YLEN;
    float* lre = scr[w][0];
    float* lim = scr[w][1];

    float xr[8], xi[8], yr[8], yi[8];
    if (f >= 2 && f <= 1021) {
        const float* src = ab + f * HOPSZ;
#pragma unroll
        for (int j = 0; j < 8; ++j) {
            int n0 = 2 * (lane + 64 * j);
            float2 s = *(const float2*)&src[n0];
            float2 w2 = *(const float2*)&win[n0];
            xr[j] = s.x * w2.x;
            xi[j] = s.y * w2.y;
        }
    } else {
#pragma unroll
        for (int j = 0; j < 8; ++j) {
            int n0 = 2 * (lane + 64 * j);
            int j0 = f * HOPSZ + n0 - 512;
            int ja = (j0 < 0) ? -j0 : ((j0 >= LOUT) ? 2 * LOUT - 2 - j0 : j0);
            int j1 = j0 + 1;
            int jb = (j1 < 0) ? -j1 : ((j1 >= LOUT) ? 2 * LOUT - 2 - j1 : j1);
            float s0 = ab[ja + 512];
            float s1 = ab[jb + 512];
            float2 w2 = *(const float2*)&win[n0];
            xr[j] = s0 * w2.x;
            xi[j] = s1 * w2.y;
        }
    }
    fft512<-1>(lre, lim, xr, xi, yr, yi, lane, tw512);

#pragma unroll
    for (int j = 0; j < 8; ++j) {
        int o = LDSIDX(lane + 64 * j);
        lre[o] = yr[j]; lim[o] = yi[j];
    }
    wsync();

    size_t row = (size_t)blk * SROW;
#pragma unroll
    for (int r = 0; r < 5; ++r) {
        int p;
        if (r < 4) p = lane + 64 * r;
        else { if (lane != 0) break; p = 256; }
        int pm = (512 - p) & 511;
        float Zkr = lre[LDSIDX(p)],  Zki = lim[LDSIDX(p)];
        float Zmr = lre[LDSIDX(pm)], Zmi = lim[LDSIDX(pm)];
        float Ar = 0.5f * (Zkr + Zmr), Ai = 0.5f * (Zki - Zmi);
        float Sr = 0.5f * (Zkr - Zmr), Si = 0.5f * (Zki + Zmi);
        float2 W1 = twh[p];
        float U1r = W1.x * Sr - W1.y * Si, U1i = W1.x * Si + W1.y * Sr;
        float Xpr = Ar + U1i, Xpi = Ai - U1r;
        float w2r, w2i;
        if (p == 0) { w2r = -1.f; w2i = 0.f; }
        else { float2 W2 = twh[512 - p]; w2r = W2.x; w2i = W2.y; }
        float U2r = -w2r * Sr - w2i * Si, U2i = w2r * Si - w2i * Sr;
        float Xqr = Ar + U2i, Xqi = -Ai - U2r;
        int q = 512 - p;
        float2 pv1 = rebprev[row + p];
        float2 pv2 = rebprev[row + q];
        float v1x = Xpr - beta * pv1.x, v1y = Xpi - beta * pv1.y;
        float v2x = Xqr - beta * pv2.x, v2y = Xqi - beta * pv2.y;
        float a1 = sqrtf(v1x * v1x + v1y * v1y) + 1e-16f;
        float a2 = sqrtf(v2x * v2x + v2y * v2y) + 1e-16f;
        float sc1 = mag[row + p] / a1;
        float sc2 = mag[row + q] / a2;
        float s1x = v1x * sc1, s1y = v1y * sc1;
        float s2x = v2x * sc2, s2y = v2y * sc2;
        rebprev[row + p] = make_float2(Xpr, Xpi);
        rebprev[row + q] = make_float2(Xqr, Xqi);
        float Apr = 0.5f * (s1x + s2x), Api = 0.5f * (s1y - s2y);
        float Spr = 0.5f * (s1x - s2x), Spi = 0.5f * (s1y + s2y);
        float Xor = W1.x * Spr + W1.y * Spi;
        float Xoi = W1.x * Spi - W1.y * Spr;
        lre[LDSIDX(p)] = Apr - Xoi;
        lim[LDSIDX(p)] = Api + Xor;
        if (p > 0) {
            float Yor = -w2r * Spr + w2i * Spi;
            float Yoi =  w2r * Spi + w2i * Spr;
            lre[LDSIDX(512 - p)] = Apr - Yoi;
            lim[LDSIDX(512 - p)] = -Api + Yor;
        }
    }
    wsync();

    fft512_lds<1>(lre, lim, xr, xi, yr, yi, lane, tw512);
    size_t frow = (size_t)blk * 1024;
#pragma unroll
    for (int j = 0; j < 8; ++j) {
        int m = lane + 64 * j;
        float2 ws = *(const float2*)&wscl[2 * m];
        float2 o;
        o.x = yr[j] * ws.x;
        o.y = yi[j] * ws.y;
        *(float2*)&frames[frow + 2 * m] = o;
    }
}

// Final overlap-add -> audio out (crop 512 each side), float4.
__global__ __launch_bounds__(256) void k_gather(const float* __restrict__ frames,
                                                const float* __restrict__ wsqinv,
                                                float* __restrict__ out)
{
    int idx = (blockIdx.x * 256 + threadIdx.x) * 4;
    if (idx >= BATCH * LOUT) return;
    int b = idx / LOUT;
    int j = idx - b * LOUT;
    int t4 = j + 512;
    const float* fb = frames + (size_t)b * (TFRAMES * 1024);
    int fhi = t4 >> 8;
    int flo = fhi - 3; if (flo < 0) flo = 0;
    if (fhi > TFRAMES - 1) fhi = TFRAMES - 1;
    float4 acc = make_float4(0.f, 0.f, 0.f, 0.f);
    for (int ff = flo; ff <= fhi; ++ff) {
        float4 v = *(const float4*)&fb[(size_t)ff * 1024 + (t4 - (ff << 8))];
        acc.x += v.x; acc.y += v.y; acc.z += v.z; acc.w += v.w;
    }
    float4 wq = *(const float4*)&wsqinv[t4];
    acc.x *= wq.x; acc.y *= wq.y; acc.z *= wq.z; acc.w *= wq.w;
    *(float4*)&out[idx] = acc;
}

// ---------------------------------------------------------------------------
extern "C" void kernel_launch(void* const* d_in, const int* in_sizes, int n_in,
                              void* d_out, int out_size, void* d_ws, size_t ws_size,
                              hipStream_t stream)
{
    const float* mel    = (const float*)d_in[0];   // [8, 80, 1024]
    const float* melinv = (const float*)d_in[1];   // [513, 80]
    const float* ang0   = (const float*)d_in[2];   // [8, 513, 1024]
    float* out = (float*)d_out;                    // [8, 261888]

    char* ws = (char*)d_ws;
    size_t off = 0;
    auto carve = [&](size_t bytes) -> void* {
        void* p = ws + off;
        off += (bytes + 255) & ~(size_t)255;
        return p;
    };
    float2* tw512   = (float2*)carve(512 * sizeof(float2));
    float2* twh     = (float2*)carve(512 * sizeof(float2));
    float*  win     = (float*) carve(1024 * sizeof(float));
    float*  wscl    = (float*) carve(1024 * sizeof(float));
    float*  wsqinv  = (float*) carve((size_t)YLEN * sizeof(float));
    float*  melinvT = (float*) carve((size_t)80 * NBINS * sizeof(float));
    float*  mag     = (float*) carve((size_t)NBLK * SROW * sizeof(float));
    float2* spec    = (float2*)carve((size_t)NBLK * SROW * sizeof(float2));
    float2* rebp    = (float2*)carve((size_t)NBLK * SROW * sizeof(float2));
    float*  frames  = (float*) carve((size_t)NBLK * 1024 * sizeof(float));
    float*  audioR  = (float*) carve((size_t)BATCH * YLEN * sizeof(float));
    (void)ws_size; (void)in_sizes; (void)n_in; (void)out_size;

    const float beta = (float)(0.99 / 1.99);

    hipLaunchKernelGGL(k_setup, dim3((YLEN + 255) / 256), dim3(256), 0, stream,
                       tw512, twh, win, wscl, melinv, melinvT, wsqinv);
    hipLaunchKernelGGL(k_specinit, dim3(TFRAMES / TT, BATCH), dim3(256), 0, stream,
                       mel, melinvT, ang0, mag, spec);
    // No rebp memset: iteration 0 uses beta=0 (0 * poisoned-float = 0 exactly;
    // validated bit-exact in round 11).

    // Initial ISTFT of Sc*angles0 → frames
    hipLaunchKernelGGL(k_ifft, dim3(NBLK / 4), dim3(256), 0, stream,
                       spec, tw512, twh, wscl, frames);
    // 32 fused GL iterations (k_oa consumes frames before k_fused overwrites)
    for (int it = 0; it < NITER; ++it) {
        float b_it = (it == 0) ? 0.f : beta;
        hipLaunchKernelGGL(k_oa, dim3((YLEN / 4 + 255) / 256, BATCH), dim3(256), 0,
                           stream, frames, wsqinv, audioR);
        hipLaunchKernelGGL(k_fused, dim3(NBLK / 4), dim3(256), 0, stream,
                           audioR, mag, tw512, twh, win, wscl, rebp, frames, b_it);
    }
    hipLaunchKernelGGL(k_gather, dim3(BATCH * LOUT / 4 / 256), dim3(256), 0, stream,
                       frames, wsqinv, out);
}